// Round 1
// baseline (27.585 us; speedup 1.0000x reference)
//
#include <hip/hip_runtime.h>
#include <math.h>

#define LEN       16384
#define NTHREADS  512
#define SEG       32          // LEN / NTHREADS
#define NWAVES    8

// exp(-1/20) and derived constants (double-precision values)
#define DECAY_F 0.951229424500714f      // d = exp(-0.05)
#define D32_F   0.20189651799465538f    // d^32 = exp(-1.6)
#define G32_F   9.1207513f              // sum_{i=1..32} d^(2i)

// Full XOR swizzle: phase-2 read addr = 32*t + i -> bank (i ^ (t&31)):
// 32 distinct banks across 64 lanes, 2 lanes/bank = conflict-free.
__device__ __forceinline__ int swz(int a) { return a ^ ((a >> 5) & 31); }

__global__ __launch_bounds__(NTHREADS) void vr_main(
    const float* __restrict__ in, const float* __restrict__ tgt,
    float* __restrict__ partial)
{
    __shared__ float smem[LEN];                 // 64 KiB
    __shared__ float wa[NWAVES], wb[NWAVES], red[NWAVES];

    const int row = blockIdx.x;
    const int tid = threadIdx.x;
    const long long rb = (long long)row * LEN;
    const float4* __restrict__ in4 = (const float4*)(in  + rb);
    const float4* __restrict__ tg4 = (const float4*)(tgt + rb);

    // ---- phase 1: coalesced float4 loads, diff -> swizzled LDS ----
    #pragma unroll
    for (int p = 0; p < LEN / 4 / NTHREADS; ++p) {
        const int idx4 = tid + p * NTHREADS;
        const float4 a = in4[idx4];
        const float4 b = tg4[idx4];
        const int base = idx4 * 4;
        smem[swz(base + 0)] = a.x - b.x;
        smem[swz(base + 1)] = a.y - b.y;
        smem[swz(base + 2)] = a.z - b.z;
        smem[swz(base + 3)] = a.w - b.w;
    }
    __syncthreads();

    // ---- phase 2: per-thread local scan + moments ----
    // s_i: local scan from 0.  True y_i = s_i + d^(i+1) * c (c = carry-in).
    // sum y_i^2 = A + 2c*B + c^2*G,  A=sum s^2, B=sum d^(i+1) s_i.
    float s = 0.f, A = 0.f, Bc = 0.f, w = 1.f;
    const int base = tid * SEG;
    #pragma unroll
    for (int i = 0; i < SEG; ++i) {
        const float x = smem[swz(base + i)];
        s = __builtin_fmaf(DECAY_F, s, x);
        w *= DECAY_F;                           // constant-folds to d^(i+1)
        A  = __builtin_fmaf(s, s, A);
        Bc = __builtin_fmaf(w, s, Bc);
    }

    // ---- affine scan of carries: f_t(c) = a*c + b, compose low->high ----
    float a = D32_F;    // d^SEG
    float b = s;        // segment end value from zero carry
    const int lane = tid & 63;
    #pragma unroll
    for (int j = 1; j < 64; j <<= 1) {
        const float au = __shfl_up(a, j);
        const float bu = __shfl_up(b, j);
        if (lane >= j) {
            b = __builtin_fmaf(a, bu, b);       // self o lower
            a *= au;
        }
    }
    const int wid = tid >> 6;
    if (lane == 63) { wa[wid] = a; wb[wid] = b; }
    __syncthreads();

    // carry entering this wave (scan 0..wid-1 wave aggregates; LDS broadcast)
    float C = 0.f;
    for (int k = 0; k < wid; ++k) C = __builtin_fmaf(wa[k], C, wb[k]);
    // exclusive intra-wave aggregate
    float aex = __shfl_up(a, 1);
    float bex = __shfl_up(b, 1);
    if (lane == 0) { aex = 1.f; bex = 0.f; }
    const float c = __builtin_fmaf(aex, C, bex);   // carry into this thread

    float part = A + 2.f * c * Bc + (c * c) * G32_F;

    // ---- block reduce (deterministic), write per-row partial ----
    #pragma unroll
    for (int j = 32; j > 0; j >>= 1) part += __shfl_down(part, j);
    if (lane == 0) red[wid] = part;
    __syncthreads();
    if (tid == 0) {
        float t = 0.f;
        #pragma unroll
        for (int k = 0; k < NWAVES; ++k) t += red[k];
        partial[row] = t;
    }
}

__global__ __launch_bounds__(1024) void vr_final(
    const float* __restrict__ partial, int n, float* __restrict__ out)
{
    __shared__ float red[16];
    const int tid = threadIdx.x;
    float v = 0.f;
    for (int k = tid; k < n; k += 1024) v += partial[k];
    #pragma unroll
    for (int j = 32; j > 0; j >>= 1) v += __shfl_down(v, j);
    const int lane = tid & 63, wid = tid >> 6;
    if (lane == 0) red[wid] = v;
    __syncthreads();
    if (tid == 0) {
        float t = 0.f;
        #pragma unroll
        for (int k = 0; k < 16; ++k) t += red[k];
        out[0] = sqrtf(t * 0.05f);   // sqrt((1/TAU) * sum * DT)
    }
}

extern "C" void kernel_launch(void* const* d_in, const int* in_sizes, int n_in,
                              void* d_out, int out_size, void* d_ws, size_t ws_size,
                              hipStream_t stream) {
    const float* in  = (const float*)d_in[0];
    const float* tgt = (const float*)d_in[1];
    float* out = (float*)d_out;
    float* ws  = (float*)d_ws;          // rows floats of scratch (4 KiB)
    const int rows = in_sizes[0] / LEN; // 1024

    vr_main<<<dim3(rows), dim3(NTHREADS), 0, stream>>>(in, tgt, ws);
    vr_final<<<dim3(1), dim3(1024), 0, stream>>>(ws, rows, out);
}